// Round 2
// baseline (2768.280 us; speedup 1.0000x reference)
//
#include <hip/hip_runtime.h>

// DGCF: N_LAYERS=1, ROUTING_ITERS=2, INTENTS=4, DK=16, K=64.
// Pipeline:
//   deg count -> dinv0 -> emb1 scatter (uniform intents) ->
//   edge affinities + softmax -> s2 -> deg2 -> dinv2 -> emb2 scatter into out (=ego).
// NOTE: edge_index arrives as int32 (JAX x64 disabled; harness passes integer
// inputs as int*). Reading it as int64 was round-1's crash.

static __global__ void k_deg(const int* __restrict__ col, int E,
                             float* __restrict__ deg) {
  int stride = gridDim.x * blockDim.x;
  for (int e = blockIdx.x * blockDim.x + threadIdx.x; e < E; e += stride)
    atomicAdd(&deg[col[e]], 1.0f);
}

// in-place: d[v] = d[v] > 0 ? rsqrt(scale*d[v]) : 0
static __global__ void k_dinv(float* __restrict__ d, int n, float scale) {
  int stride = gridDim.x * blockDim.x;
  for (int v = blockIdx.x * blockDim.x + threadIdx.x; v < n; v += stride) {
    float x = d[v];
    d[v] = x > 0.f ? rsqrtf(scale * x) : 0.f;
  }
}

// iter-1 propagation: emb1[c*64+d] += 0.25*dinv0[r]*dinv0[c]*x0[r*64+d]
static __global__ void k_emb1(const int* __restrict__ row,
                              const int* __restrict__ col, int E,
                              const float* __restrict__ dinv0,
                              const float* __restrict__ x0,
                              float* __restrict__ emb1) {
  long long total = (long long)E << 6;
  long long stride = (long long)gridDim.x * blockDim.x;
  for (long long t = (long long)blockIdx.x * blockDim.x + threadIdx.x; t < total;
       t += stride) {
    int e = (int)(t >> 6), d = (int)(t & 63);
    int r = row[e], c = col[e];
    float w = 0.25f * dinv0[r] * dinv0[c];
    atomicAdd(&emb1[(size_t)c * 64 + d], w * x0[(size_t)r * 64 + d]);
  }
}

// per half-edge j: ui[k]=<emb1[u],tanh(x0[i])>_k, iu[k]=<emb1[i],tanh(x0[u])>_k
// then s2[j] = softmax_k(ui), s2[j+H] = softmax_k(iu)
static __global__ void k_inter(const int* __restrict__ row,
                               const int* __restrict__ col, int H,
                               const float* __restrict__ emb1,
                               const float* __restrict__ x0,
                               float* __restrict__ s2) {
  int stride = gridDim.x * blockDim.x;
  for (int j = blockIdx.x * blockDim.x + threadIdx.x; j < H; j += stride) {
    int u = row[j], i = col[j];
    const float4* e1u = (const float4*)(emb1 + (size_t)u * 64);
    const float4* e1i = (const float4*)(emb1 + (size_t)i * 64);
    const float4* xu = (const float4*)(x0 + (size_t)u * 64);
    const float4* xi = (const float4*)(x0 + (size_t)i * 64);
    float ui[4], iu[4];
#pragma unroll
    for (int k = 0; k < 4; ++k) {
      float su = 0.f, si = 0.f;
#pragma unroll
      for (int q = 0; q < 4; ++q) {
        float4 a = e1u[k * 4 + q];
        float4 b = xi[k * 4 + q];
        su += a.x * tanhf(b.x) + a.y * tanhf(b.y) + a.z * tanhf(b.z) +
              a.w * tanhf(b.w);
        float4 c = e1i[k * 4 + q];
        float4 dd = xu[k * 4 + q];
        si += c.x * tanhf(dd.x) + c.y * tanhf(dd.y) + c.z * tanhf(dd.z) +
              c.w * tanhf(dd.w);
      }
      ui[k] = su;
      iu[k] = si;
    }
    float m1 = fmaxf(fmaxf(ui[0], ui[1]), fmaxf(ui[2], ui[3]));
    float m2 = fmaxf(fmaxf(iu[0], iu[1]), fmaxf(iu[2], iu[3]));
    float p1[4], p2[4];
    float t1 = 0.f, t2 = 0.f;
#pragma unroll
    for (int k = 0; k < 4; ++k) {
      p1[k] = expf(ui[k] - m1);
      t1 += p1[k];
      p2[k] = expf(iu[k] - m2);
      t2 += p2[k];
    }
#pragma unroll
    for (int k = 0; k < 4; ++k) {
      s2[(size_t)j * 4 + k] = p1[k] / t1;
      s2[((size_t)j + H) * 4 + k] = p2[k] / t2;
    }
  }
}

static __global__ void k_deg2(const int* __restrict__ col, int E,
                              const float* __restrict__ s2,
                              float* __restrict__ deg2) {
  int stride = gridDim.x * blockDim.x;
  for (int e = blockIdx.x * blockDim.x + threadIdx.x; e < E; e += stride) {
    int c = col[e];
    float4 s = ((const float4*)s2)[e];
    atomicAdd(&deg2[(size_t)c * 4 + 0], s.x);
    atomicAdd(&deg2[(size_t)c * 4 + 1], s.y);
    atomicAdd(&deg2[(size_t)c * 4 + 2], s.z);
    atomicAdd(&deg2[(size_t)c * 4 + 3], s.w);
  }
}

// iter-2 propagation into out (pre-initialized with ego):
// out[c*64+d] += dinv2[r*4+k]*dinv2[c*4+k]*s2[e*4+k]*x0[r*64+d], k=d>>4
static __global__ void k_emb2(const int* __restrict__ row,
                              const int* __restrict__ col, int E,
                              const float* __restrict__ dinv2,
                              const float* __restrict__ s2,
                              const float* __restrict__ x0,
                              float* __restrict__ out) {
  long long total = (long long)E << 6;
  long long stride = (long long)gridDim.x * blockDim.x;
  for (long long t = (long long)blockIdx.x * blockDim.x + threadIdx.x; t < total;
       t += stride) {
    int e = (int)(t >> 6), d = (int)(t & 63);
    int k = d >> 4;
    int r = row[e], c = col[e];
    float w = dinv2[(size_t)r * 4 + k] * dinv2[(size_t)c * 4 + k] *
              s2[(size_t)e * 4 + k];
    atomicAdd(&out[(size_t)c * 64 + d], w * x0[(size_t)r * 64 + d]);
  }
}

extern "C" void kernel_launch(void* const* d_in, const int* in_sizes, int n_in,
                              void* d_out, int out_size, void* d_ws,
                              size_t ws_size, hipStream_t stream) {
  const float* Gu = (const float*)d_in[0];
  const float* Gi = (const float*)d_in[1];
  const int* ei = (const int*)d_in[2];
  float* out = (float*)d_out;

  const int K = 64;
  int nu = in_sizes[0] / K;  // 100000
  int ni = in_sizes[1] / K;  // 50000
  int n = nu + ni;           // 150000
  int E = in_sizes[2] / 2;   // 2,000,000
  int H = E / 2;             // 1,000,000
  const int* row = ei;
  const int* col = ei + E;

  // workspace layout (floats): x0[n*64] | emb1[n*64] | s2[E*4] | dinv0[n] | dinv2[n*4]
  float* x0 = (float*)d_ws;
  float* emb1 = x0 + (size_t)n * K;
  float* s2 = emb1 + (size_t)n * K;
  float* dinv0 = s2 + (size_t)E * 4;
  float* dinv2 = dinv0 + n;
  // total = 2*9.6M + 8M + 0.15M + 0.6M floats ~= 112 MB

  // init: x0 = concat(Gu, Gi); out = ego (= x0); zero accumulators
  hipMemcpyAsync(x0, Gu, (size_t)nu * K * sizeof(float),
                 hipMemcpyDeviceToDevice, stream);
  hipMemcpyAsync(x0 + (size_t)nu * K, Gi, (size_t)ni * K * sizeof(float),
                 hipMemcpyDeviceToDevice, stream);
  hipMemcpyAsync(out, x0, (size_t)n * K * sizeof(float),
                 hipMemcpyDeviceToDevice, stream);
  hipMemsetAsync(emb1, 0, (size_t)n * K * sizeof(float), stream);
  hipMemsetAsync(dinv0, 0, (size_t)n * sizeof(float), stream);
  hipMemsetAsync(dinv2, 0, (size_t)n * 4 * sizeof(float), stream);

  const int B = 256;
  int gE = min((E + B - 1) / B, 4096);
  int gN = min((n + B - 1) / B, 1024);
  int gBig = 8192;  // grid-stride over E*64 work items
  int gH = min((H + B - 1) / B, 4096);

  // ---- routing iter 1 (uniform intents) ----
  k_deg<<<gE, B, 0, stream>>>(col, E, dinv0);
  k_dinv<<<gN, B, 0, stream>>>(dinv0, n, 0.25f);
  k_emb1<<<gBig, B, 0, stream>>>(row, col, E, dinv0, x0, emb1);

  // ---- affinities -> s2 ----
  k_inter<<<gH, B, 0, stream>>>(row, col, H, emb1, x0, s2);

  // ---- routing iter 2 ----
  k_deg2<<<gE, B, 0, stream>>>(col, E, s2, dinv2);
  k_dinv<<<gN, B, 0, stream>>>(dinv2, n * 4, 1.0f);
  k_emb2<<<gBig, B, 0, stream>>>(row, col, E, dinv2, s2, x0, out);
}

// Round 3
// 1521.939 us; speedup vs baseline: 1.8189x; 1.8189x over previous
//
#include <hip/hip_runtime.h>

// DGCF: N_LAYERS=1, ROUTING_ITERS=2, INTENTS=4, DK=16, K=64.
// Round 3: bf16 gather tables (x0h, t0h=tanh(x0), e1h=emb1, s2h) +
// wave-cooperative k_inter (32 lanes/edge, coalesced 128B row reads).
// edge_index is int32.

__device__ __forceinline__ float bf2f(unsigned short h) {
  return __uint_as_float((unsigned)h << 16);
}
__device__ __forceinline__ unsigned short f2bf(float x) {
  unsigned u = __float_as_uint(x);
  return (unsigned short)((u + 0x7FFFu + ((u >> 16) & 1u)) >> 16);
}

// x0h = bf16(ego), t0h = bf16(tanh(ego)); ego lives in `out`
static __global__ void k_cvt(const float* __restrict__ ego, long long total,
                             unsigned short* __restrict__ x0h,
                             unsigned short* __restrict__ t0h) {
  long long stride = (long long)gridDim.x * blockDim.x;
  for (long long t = (long long)blockIdx.x * blockDim.x + threadIdx.x; t < total;
       t += stride) {
    float v = ego[t];
    x0h[t] = f2bf(v);
    t0h[t] = f2bf(tanhf(v));
  }
}

static __global__ void k_cvt1(const float* __restrict__ src, long long total,
                              unsigned short* __restrict__ dst) {
  long long stride = (long long)gridDim.x * blockDim.x;
  for (long long t = (long long)blockIdx.x * blockDim.x + threadIdx.x; t < total;
       t += stride)
    dst[t] = f2bf(src[t]);
}

static __global__ void k_deg(const int* __restrict__ col, int E,
                             float* __restrict__ deg) {
  int stride = gridDim.x * blockDim.x;
  for (int e = blockIdx.x * blockDim.x + threadIdx.x; e < E; e += stride)
    atomicAdd(&deg[col[e]], 1.0f);
}

// in-place: d[v] = d[v] > 0 ? rsqrt(scale*d[v]) : 0
static __global__ void k_dinv(float* __restrict__ d, int n, float scale) {
  int stride = gridDim.x * blockDim.x;
  for (int v = blockIdx.x * blockDim.x + threadIdx.x; v < n; v += stride) {
    float x = d[v];
    d[v] = x > 0.f ? rsqrtf(scale * x) : 0.f;
  }
}

// iter-1 propagation: emb1[c*64+d] += 0.25*dinv0[r]*dinv0[c]*x0[r*64+d]
static __global__ void k_emb1(const int* __restrict__ row,
                              const int* __restrict__ col, int E,
                              const float* __restrict__ dinv0,
                              const unsigned short* __restrict__ x0h,
                              float* __restrict__ emb1) {
  long long total = (long long)E << 6;
  long long stride = (long long)gridDim.x * blockDim.x;
  for (long long t = (long long)blockIdx.x * blockDim.x + threadIdx.x; t < total;
       t += stride) {
    int e = (int)(t >> 6), d = (int)(t & 63);
    int r = row[e], c = col[e];
    float w = 0.25f * dinv0[r] * dinv0[c];
    atomicAdd(&emb1[(size_t)c * 64 + d], w * bf2f(x0h[(size_t)r * 64 + d]));
  }
}

// wave-cooperative affinity+softmax. 32 lanes per half-edge j:
//   lanes 0-15:  ui = <emb1[u], tanh(x0[i])>  -> s2[j]
//   lanes 16-31: iu = <emb1[i], tanh(x0[u])>  -> s2[j+H]
// lane q of 16 loads ushort4 (elements 4q..4q+3, intent k=q>>2).
static __global__ void k_inter(const int* __restrict__ row,
                               const int* __restrict__ col, int H,
                               const unsigned short* __restrict__ e1h,
                               const unsigned short* __restrict__ t0h,
                               unsigned short* __restrict__ s2h) {
  int tid = threadIdx.x;
  int lane = tid & 63;
  int wave = tid >> 6;
  int j = blockIdx.x * 8 + wave * 2 + (lane >> 5);
  if (j >= H) return;
  int sub = lane & 31;
  int half = sub >> 4;  // 0: ui, 1: iu
  int q = sub & 15;
  int u = row[j], i = col[j];
  int an = half ? i : u;  // emb1 node
  int bn = half ? u : i;  // tanh node
  ushort4 av = *(const ushort4*)(e1h + (size_t)an * 64 + 4 * q);
  ushort4 bv = *(const ushort4*)(t0h + (size_t)bn * 64 + 4 * q);
  float partial = bf2f(av.x) * bf2f(bv.x) + bf2f(av.y) * bf2f(bv.y) +
                  bf2f(av.z) * bf2f(bv.z) + bf2f(av.w) * bf2f(bv.w);
  // reduce over the 4-lane group -> intent sum (k = q>>2)
  partial += __shfl_xor(partial, 1);
  partial += __shfl_xor(partial, 2);
  // collect 4 intent sums into every lane of the 16-group
  int base = lane & ~15;
  float v0 = __shfl(partial, base + 0);
  float v1 = __shfl(partial, base + 4);
  float v2 = __shfl(partial, base + 8);
  float v3 = __shfl(partial, base + 12);
  float m = fmaxf(fmaxf(v0, v1), fmaxf(v2, v3));
  float p0 = expf(v0 - m), p1 = expf(v1 - m), p2 = expf(v2 - m),
        p3 = expf(v3 - m);
  float inv = 1.0f / (p0 + p1 + p2 + p3);
  if (q < 4) {
    float pq = (q == 0 ? p0 : q == 1 ? p1 : q == 2 ? p2 : p3) * inv;
    size_t dst = (size_t)(half ? j + H : j) * 4 + q;
    s2h[dst] = f2bf(pq);
  }
}

static __global__ void k_deg2(const int* __restrict__ col, int E,
                              const unsigned short* __restrict__ s2h,
                              float* __restrict__ deg2) {
  int stride = gridDim.x * blockDim.x;
  for (int e = blockIdx.x * blockDim.x + threadIdx.x; e < E; e += stride) {
    int c = col[e];
    ushort4 s = ((const ushort4*)s2h)[e];
    atomicAdd(&deg2[(size_t)c * 4 + 0], bf2f(s.x));
    atomicAdd(&deg2[(size_t)c * 4 + 1], bf2f(s.y));
    atomicAdd(&deg2[(size_t)c * 4 + 2], bf2f(s.z));
    atomicAdd(&deg2[(size_t)c * 4 + 3], bf2f(s.w));
  }
}

// iter-2 propagation into out (pre-initialized with ego):
// out[c*64+d] += dinv2[r*4+k]*dinv2[c*4+k]*s2[e*4+k]*x0[r*64+d], k=d>>4
static __global__ void k_emb2(const int* __restrict__ row,
                              const int* __restrict__ col, int E,
                              const float* __restrict__ dinv2,
                              const unsigned short* __restrict__ s2h,
                              const unsigned short* __restrict__ x0h,
                              float* __restrict__ out) {
  long long total = (long long)E << 6;
  long long stride = (long long)gridDim.x * blockDim.x;
  for (long long t = (long long)blockIdx.x * blockDim.x + threadIdx.x; t < total;
       t += stride) {
    int e = (int)(t >> 6), d = (int)(t & 63);
    int k = d >> 4;
    int r = row[e], c = col[e];
    float w = dinv2[(size_t)r * 4 + k] * dinv2[(size_t)c * 4 + k] *
              bf2f(s2h[(size_t)e * 4 + k]);
    atomicAdd(&out[(size_t)c * 64 + d], w * bf2f(x0h[(size_t)r * 64 + d]));
  }
}

extern "C" void kernel_launch(void* const* d_in, const int* in_sizes, int n_in,
                              void* d_out, int out_size, void* d_ws,
                              size_t ws_size, hipStream_t stream) {
  const float* Gu = (const float*)d_in[0];
  const float* Gi = (const float*)d_in[1];
  const int* ei = (const int*)d_in[2];
  float* out = (float*)d_out;

  const int K = 64;
  int nu = in_sizes[0] / K;  // 100000
  int ni = in_sizes[1] / K;  // 50000
  int n = nu + ni;           // 150000
  int E = in_sizes[2] / 2;   // 2,000,000
  int H = E / 2;             // 1,000,000
  const int* row = ei;
  const int* col = ei + E;
  long long nK = (long long)n * K;

  // ws layout: emb1 f32[n*64] | dinv0 f32[n] | dinv2 f32[n*4] |
  //            s2h u16[E*4] | x0h u16[n*64] | t0h u16[n*64] | e1h u16[n*64]
  // total ~115 MB
  float* emb1 = (float*)d_ws;
  float* dinv0 = emb1 + nK;
  float* dinv2 = dinv0 + n;
  unsigned short* s2h = (unsigned short*)(dinv2 + (size_t)n * 4);
  unsigned short* x0h = s2h + (size_t)E * 4;
  unsigned short* t0h = x0h + nK;
  unsigned short* e1h = t0h + nK;

  // out = ego = concat(Gu, Gi)
  hipMemcpyAsync(out, Gu, (size_t)nu * K * sizeof(float),
                 hipMemcpyDeviceToDevice, stream);
  hipMemcpyAsync(out + (size_t)nu * K, Gi, (size_t)ni * K * sizeof(float),
                 hipMemcpyDeviceToDevice, stream);
  hipMemsetAsync(emb1, 0, nK * sizeof(float), stream);
  hipMemsetAsync(dinv0, 0, (size_t)n * sizeof(float), stream);
  hipMemsetAsync(dinv2, 0, (size_t)n * 4 * sizeof(float), stream);

  const int B = 256;
  int gE = min((E + B - 1) / B, 4096);
  int gN = min((n + B - 1) / B, 1024);
  int gBig = 8192;
  int gCvt = 2048;

  k_cvt<<<gCvt, B, 0, stream>>>(out, nK, x0h, t0h);

  // ---- routing iter 1 (uniform intents) ----
  k_deg<<<gE, B, 0, stream>>>(col, E, dinv0);
  k_dinv<<<gN, B, 0, stream>>>(dinv0, n, 0.25f);
  k_emb1<<<gBig, B, 0, stream>>>(row, col, E, dinv0, x0h, emb1);
  k_cvt1<<<gCvt, B, 0, stream>>>(emb1, nK, e1h);

  // ---- affinities -> s2 (8 edges per 256-thread block) ----
  int gInter = (H + 7) / 8;
  k_inter<<<gInter, B, 0, stream>>>(row, col, H, e1h, t0h, s2h);

  // ---- routing iter 2 ----
  k_deg2<<<gE, B, 0, stream>>>(col, E, s2h, dinv2);
  k_dinv<<<gN, B, 0, stream>>>(dinv2, n * 4, 1.0f);
  k_emb2<<<gBig, B, 0, stream>>>(row, col, E, dinv2, s2h, x0h, out);
}

// Round 4
// 859.594 us; speedup vs baseline: 3.2204x; 1.7705x over previous
//
#include <hip/hip_runtime.h>

// DGCF round 4: CSR gather replaces all large atomic scatters.
//   cnt -> segment alloc (no scan; segment order arbitrary) -> fill perm/prow
//   gather1: e1h[v] = bf16(0.25*dinv0[v]*sum dinv0[r]*x0[r])   (wave/node)
//   k_inter: edge affinities + softmax -> s2h (bf16)
//   deg2csr: dinv2 from CSR (no atomics)
//   gather2: out[v] += dinv2[v,k]*sum dinv2[r,k]*s2[e,k]*x0[r] (wave/node)
// edge_index is int32.

__device__ __forceinline__ float bf2f(unsigned short h) {
  return __uint_as_float((unsigned)h << 16);
}
__device__ __forceinline__ unsigned short f2bf(float x) {
  unsigned u = __float_as_uint(x);
  return (unsigned short)((u + 0x7FFFu + ((u >> 16) & 1u)) >> 16);
}

// x0h = bf16(ego), t0h = bf16(tanh(ego)); ego lives in `out`
static __global__ void k_cvt(const float* __restrict__ ego, long long total,
                             unsigned short* __restrict__ x0h,
                             unsigned short* __restrict__ t0h) {
  long long stride = (long long)gridDim.x * blockDim.x;
  for (long long t = (long long)blockIdx.x * blockDim.x + threadIdx.x; t < total;
       t += stride) {
    float v = ego[t];
    x0h[t] = f2bf(v);
    t0h[t] = f2bf(tanhf(v));
  }
}

static __global__ void k_cnt(const int* __restrict__ col, int E,
                             int* __restrict__ cnt) {
  int stride = gridDim.x * blockDim.x;
  for (int e = blockIdx.x * blockDim.x + threadIdx.x; e < E; e += stride)
    atomicAdd(&cnt[col[e]], 1);
}

// segment allocation + dinv0. Segment order across nodes is arbitrary
// (atomicAdd on a global counter) — only within-segment contiguity matters.
static __global__ void k_alloc(const int* __restrict__ cnt, int n,
                               int* __restrict__ off, int* __restrict__ cursor,
                               float* __restrict__ dinv0f,
                               int* __restrict__ ctr) {
  int stride = gridDim.x * blockDim.x;
  for (int v = blockIdx.x * blockDim.x + threadIdx.x; v < n; v += stride) {
    int c = cnt[v];
    int o = atomicAdd(ctr, c);
    off[v] = o;
    cursor[v] = o;
    dinv0f[v] = c > 0 ? rsqrtf(0.25f * (float)c) : 0.f;
  }
}

static __global__ void k_fill(const int* __restrict__ row,
                              const int* __restrict__ col, int E,
                              int* __restrict__ cursor, int* __restrict__ perm,
                              int* __restrict__ prow) {
  int stride = gridDim.x * blockDim.x;
  for (int e = blockIdx.x * blockDim.x + threadIdx.x; e < E; e += stride) {
    int p = atomicAdd(&cursor[col[e]], 1);
    perm[p] = e;
    prow[p] = row[e];
  }
}

// wave per node, lane = dim. e1h[v*64+d] = bf16(0.25*dinv0[v]*sum dinv0[r]*x0[r,d])
static __global__ void k_gather1(const int* __restrict__ off,
                                 const int* __restrict__ cnt,
                                 const int* __restrict__ prow, int n,
                                 const float* __restrict__ dinv0f,
                                 const unsigned short* __restrict__ x0h,
                                 unsigned short* __restrict__ e1h) {
  int lane = threadIdx.x & 63;
  int wstride = (gridDim.x * blockDim.x) >> 6;
  for (int v = (blockIdx.x * blockDim.x + threadIdx.x) >> 6; v < n;
       v += wstride) {
    int o = off[v], c = cnt[v];
    float acc = 0.f;
    for (int t = 0; t < c; ++t) {
      int r = prow[o + t];
      acc += dinv0f[r] * bf2f(x0h[(size_t)r * 64 + lane]);
    }
    e1h[(size_t)v * 64 + lane] = f2bf(0.25f * dinv0f[v] * acc);
  }
}

// wave-cooperative affinity+softmax. 32 lanes per half-edge j:
//   lanes 0-15:  ui = <emb1[u], tanh(x0[i])>  -> s2[j]
//   lanes 16-31: iu = <emb1[i], tanh(x0[u])>  -> s2[j+H]
static __global__ void k_inter(const int* __restrict__ row,
                               const int* __restrict__ col, int H,
                               const unsigned short* __restrict__ e1h,
                               const unsigned short* __restrict__ t0h,
                               unsigned short* __restrict__ s2h) {
  int tid = threadIdx.x;
  int lane = tid & 63;
  int wave = tid >> 6;
  int j = blockIdx.x * 8 + wave * 2 + (lane >> 5);
  if (j >= H) return;
  int sub = lane & 31;
  int half = sub >> 4;  // 0: ui, 1: iu
  int q = sub & 15;
  int u = row[j], i = col[j];
  int an = half ? i : u;  // emb1 node
  int bn = half ? u : i;  // tanh node
  ushort4 av = *(const ushort4*)(e1h + (size_t)an * 64 + 4 * q);
  ushort4 bv = *(const ushort4*)(t0h + (size_t)bn * 64 + 4 * q);
  float partial = bf2f(av.x) * bf2f(bv.x) + bf2f(av.y) * bf2f(bv.y) +
                  bf2f(av.z) * bf2f(bv.z) + bf2f(av.w) * bf2f(bv.w);
  partial += __shfl_xor(partial, 1);
  partial += __shfl_xor(partial, 2);
  int base = lane & ~15;
  float v0 = __shfl(partial, base + 0);
  float v1 = __shfl(partial, base + 4);
  float v2 = __shfl(partial, base + 8);
  float v3 = __shfl(partial, base + 12);
  float m = fmaxf(fmaxf(v0, v1), fmaxf(v2, v3));
  float p0 = expf(v0 - m), p1 = expf(v1 - m), p2 = expf(v2 - m),
        p3 = expf(v3 - m);
  float inv = 1.0f / (p0 + p1 + p2 + p3);
  if (q < 4) {
    float pq = (q == 0 ? p0 : q == 1 ? p1 : q == 2 ? p2 : p3) * inv;
    size_t dst = (size_t)(half ? j + H : j) * 4 + q;
    s2h[dst] = f2bf(pq);
  }
}

// thread per node: deg2[v,k] = sum_{e in seg(v)} s2[e,k]; dinv2 = rsqrt(>0)
static __global__ void k_deg2csr(const int* __restrict__ off,
                                 const int* __restrict__ cnt,
                                 const int* __restrict__ perm, int n,
                                 const unsigned short* __restrict__ s2h,
                                 float* __restrict__ dinv2) {
  int stride = gridDim.x * blockDim.x;
  for (int v = blockIdx.x * blockDim.x + threadIdx.x; v < n; v += stride) {
    int o = off[v], c = cnt[v];
    float s0 = 0.f, s1 = 0.f, s2 = 0.f, s3 = 0.f;
    for (int t = 0; t < c; ++t) {
      int e = perm[o + t];
      ushort4 w = ((const ushort4*)s2h)[e];
      s0 += bf2f(w.x);
      s1 += bf2f(w.y);
      s2 += bf2f(w.z);
      s3 += bf2f(w.w);
    }
    dinv2[(size_t)v * 4 + 0] = s0 > 0.f ? rsqrtf(s0) : 0.f;
    dinv2[(size_t)v * 4 + 1] = s1 > 0.f ? rsqrtf(s1) : 0.f;
    dinv2[(size_t)v * 4 + 2] = s2 > 0.f ? rsqrtf(s2) : 0.f;
    dinv2[(size_t)v * 4 + 3] = s3 > 0.f ? rsqrtf(s3) : 0.f;
  }
}

// wave per node, lane = dim, k = lane>>4.
// out[v*64+d] += dinv2[v,k] * sum dinv2[r,k]*s2[e,k]*x0[r,d]
static __global__ void k_gather2(const int* __restrict__ off,
                                 const int* __restrict__ cnt,
                                 const int* __restrict__ perm,
                                 const int* __restrict__ prow, int n,
                                 const float* __restrict__ dinv2,
                                 const unsigned short* __restrict__ s2h,
                                 const unsigned short* __restrict__ x0h,
                                 float* __restrict__ out) {
  int lane = threadIdx.x & 63;
  int k = lane >> 4;
  int wstride = (gridDim.x * blockDim.x) >> 6;
  for (int v = (blockIdx.x * blockDim.x + threadIdx.x) >> 6; v < n;
       v += wstride) {
    int o = off[v], c = cnt[v];
    float acc = 0.f;
    for (int t = 0; t < c; ++t) {
      int p = o + t;
      int e = perm[p];
      int r = prow[p];
      float w = dinv2[(size_t)r * 4 + k] * bf2f(s2h[(size_t)e * 4 + k]);
      acc += w * bf2f(x0h[(size_t)r * 64 + lane]);
    }
    size_t d = (size_t)v * 64 + lane;
    out[d] += dinv2[(size_t)v * 4 + k] * acc;
  }
}

extern "C" void kernel_launch(void* const* d_in, const int* in_sizes, int n_in,
                              void* d_out, int out_size, void* d_ws,
                              size_t ws_size, hipStream_t stream) {
  const float* Gu = (const float*)d_in[0];
  const float* Gi = (const float*)d_in[1];
  const int* ei = (const int*)d_in[2];
  float* out = (float*)d_out;

  const int K = 64;
  int nu = in_sizes[0] / K;  // 100000
  int ni = in_sizes[1] / K;  // 50000
  int n = nu + ni;           // 150000
  int E = in_sizes[2] / 2;   // 2,000,000
  int H = E / 2;             // 1,000,000
  const int* row = ei;
  const int* col = ei + E;
  long long nK = (long long)n * K;

  // ws layout (bytes, 16-aligned): dinv0f f32[n] | dinv2 f32[4n] | cnt[n] |
  //   off[n] | cursor[n] | ctr[4] | perm[E] | prow[E] | s2h u16[4E] |
  //   x0h u16[nK] | t0h u16[nK] | e1h u16[nK]   (~94 MB)
  float* dinv0f = (float*)d_ws;
  float* dinv2 = dinv0f + n;
  int* cnt = (int*)(dinv2 + (size_t)n * 4);
  int* off = cnt + n;
  int* cursor = off + n;
  int* ctr = cursor + n;  // 4 ints (padding for alignment)
  int* perm = ctr + 4;
  int* prow = perm + E;
  unsigned short* s2h = (unsigned short*)(prow + E);
  unsigned short* x0h = s2h + (size_t)E * 4;
  unsigned short* t0h = x0h + nK;
  unsigned short* e1h = t0h + nK;

  // out = ego = concat(Gu, Gi)
  hipMemcpyAsync(out, Gu, (size_t)nu * K * sizeof(float),
                 hipMemcpyDeviceToDevice, stream);
  hipMemcpyAsync(out + (size_t)nu * K, Gi, (size_t)ni * K * sizeof(float),
                 hipMemcpyDeviceToDevice, stream);
  hipMemsetAsync(cnt, 0, (size_t)n * sizeof(int), stream);
  hipMemsetAsync(ctr, 0, 4 * sizeof(int), stream);

  const int B = 256;
  int gE = min((E + B - 1) / B, 4096);
  int gN = (n + B - 1) / B;  // 586
  int gW = (n + 3) / 4;      // wave-per-node grids (4 waves/block)

  k_cvt<<<2048, B, 0, stream>>>(out, nK, x0h, t0h);

  // ---- CSR build ----
  k_cnt<<<gE, B, 0, stream>>>(col, E, cnt);
  k_alloc<<<gN, B, 0, stream>>>(cnt, n, off, cursor, dinv0f, ctr);
  k_fill<<<gE, B, 0, stream>>>(row, col, E, cursor, perm, prow);

  // ---- routing iter 1 (uniform intents) -> e1h ----
  k_gather1<<<gW, B, 0, stream>>>(off, cnt, prow, n, dinv0f, x0h, e1h);

  // ---- affinities -> s2 ----
  int gInter = (H + 7) / 8;
  k_inter<<<gInter, B, 0, stream>>>(row, col, H, e1h, t0h, s2h);

  // ---- routing iter 2 ----
  k_deg2csr<<<gN, B, 0, stream>>>(off, cnt, perm, n, s2h, dinv2);
  k_gather2<<<gW, B, 0, stream>>>(off, cnt, perm, prow, n, dinv2, s2h, x0h,
                                  out);
}

// Round 5
// 592.189 us; speedup vs baseline: 4.6747x; 1.4516x over previous
//
#include <hip/hip_runtime.h>

// DGCF round 5: node-centric everything, 16-lane x 4-edge gather waves.
//   CSR build (cnt/alloc/fill -> prow only)
//   k_cvt:    x0h = bf16(ego), y0h = bf16(dinv0*ego)
//   gather1:  e1h[v] = bf16(0.25*dinv0[v]*sum_seg y0[r])        (wave/node)
//   k_score:  s2csr[p] = softmax_k<e1h[prow[p]], tanh(x0[v])>;  (wave/node)
//             dinv2[v] = rsqrt(sum_seg s2) fused
//   k_zbuild: z0h = bf16(dinv2[.,k]*x0)
//   gather2:  out[v] += dinv2[v,k]*sum_seg s2csr[p,k]*z0[r]     (wave/node)
// Per-edge random traffic: one 128B row read per gather/score loop iteration,
// 4 rows in flight per wave (lane q=dim-quad, g=edge subgroup).
// edge_index is int32.

__device__ __forceinline__ float bf2f(unsigned short h) {
  return __uint_as_float((unsigned)h << 16);
}
__device__ __forceinline__ unsigned short f2bf(float x) {
  unsigned u = __float_as_uint(x);
  return (unsigned short)((u + 0x7FFFu + ((u >> 16) & 1u)) >> 16);
}

static __global__ void k_cnt(const int* __restrict__ col, int E,
                             int* __restrict__ cnt) {
  int stride = gridDim.x * blockDim.x;
  for (int e = blockIdx.x * blockDim.x + threadIdx.x; e < E; e += stride)
    atomicAdd(&cnt[col[e]], 1);
}

// segment allocation + dinv0. Segment order arbitrary (atomic ctr);
// only within-segment contiguity matters.
static __global__ void k_alloc(const int* __restrict__ cnt, int n,
                               int* __restrict__ off, int* __restrict__ cursor,
                               float* __restrict__ dinv0f,
                               int* __restrict__ ctr) {
  int stride = gridDim.x * blockDim.x;
  for (int v = blockIdx.x * blockDim.x + threadIdx.x; v < n; v += stride) {
    int c = cnt[v];
    int o = atomicAdd(ctr, c);
    off[v] = o;
    cursor[v] = o;
    dinv0f[v] = c > 0 ? rsqrtf(0.25f * (float)c) : 0.f;
  }
}

static __global__ void k_fill(const int* __restrict__ row,
                              const int* __restrict__ col, int E,
                              int* __restrict__ cursor,
                              int* __restrict__ prow) {
  int stride = gridDim.x * blockDim.x;
  for (int e = blockIdx.x * blockDim.x + threadIdx.x; e < E; e += stride) {
    int p = atomicAdd(&cursor[col[e]], 1);
    prow[p] = row[e];
  }
}

// x0h = bf16(ego), y0h = bf16(dinv0[node]*ego)
static __global__ void k_cvt(const float* __restrict__ ego,
                             const float* __restrict__ dinv0f, long long total,
                             unsigned short* __restrict__ x0h,
                             unsigned short* __restrict__ y0h) {
  long long stride = (long long)gridDim.x * blockDim.x;
  for (long long t = (long long)blockIdx.x * blockDim.x + threadIdx.x; t < total;
       t += stride) {
    float v = ego[t];
    x0h[t] = f2bf(v);
    y0h[t] = f2bf(dinv0f[t >> 6] * v);
  }
}

// wave/node: e1h[v*64+d] = bf16(0.25*dinv0[v] * sum_seg y0[r*64+d])
static __global__ void k_gather1(const int* __restrict__ off,
                                 const int* __restrict__ cnt,
                                 const int* __restrict__ prow, int n,
                                 const float* __restrict__ dinv0f,
                                 const unsigned short* __restrict__ y0h,
                                 unsigned short* __restrict__ e1h) {
  int lane = threadIdx.x & 63;
  int q = lane & 15, g = lane >> 4;
  int wstride = (gridDim.x * blockDim.x) >> 6;
  for (int v = (blockIdx.x * blockDim.x + threadIdx.x) >> 6; v < n;
       v += wstride) {
    int o = off[v], c = cnt[v];
    float a0 = 0.f, a1 = 0.f, a2 = 0.f, a3 = 0.f;
    for (int t = g; t < c; t += 4) {
      int r = prow[o + t];
      ushort4 yv = *(const ushort4*)(y0h + (size_t)r * 64 + 4 * q);
      a0 += bf2f(yv.x);
      a1 += bf2f(yv.y);
      a2 += bf2f(yv.z);
      a3 += bf2f(yv.w);
    }
    a0 += __shfl_xor(a0, 16); a0 += __shfl_xor(a0, 32);
    a1 += __shfl_xor(a1, 16); a1 += __shfl_xor(a1, 32);
    a2 += __shfl_xor(a2, 16); a2 += __shfl_xor(a2, 32);
    a3 += __shfl_xor(a3, 16); a3 += __shfl_xor(a3, 32);
    if (g == 0) {
      float sc = 0.25f * dinv0f[v];
      ushort4 ov;
      ov.x = f2bf(sc * a0);
      ov.y = f2bf(sc * a1);
      ov.z = f2bf(sc * a2);
      ov.w = f2bf(sc * a3);
      *(ushort4*)(e1h + (size_t)v * 64 + 4 * q) = ov;
    }
  }
}

// wave/node: for each CSR pos p in seg(v) (source r):
//   score_k = <e1h[r], tanh(x0[v])>_k  (this is ui for items, iu for users)
//   s2csr[p] = softmax_k(score); dinv2[v] = rsqrt(sum_seg s2) fused.
static __global__ void k_score(const int* __restrict__ off,
                               const int* __restrict__ cnt,
                               const int* __restrict__ prow, int n,
                               const unsigned short* __restrict__ e1h,
                               const unsigned short* __restrict__ x0h,
                               unsigned short* __restrict__ s2csr,
                               float* __restrict__ dinv2) {
  int lane = threadIdx.x & 63;
  int q = lane & 15, g = lane >> 4, k = q >> 2;
  int wstride = (gridDim.x * blockDim.x) >> 6;
  for (int v = (blockIdx.x * blockDim.x + threadIdx.x) >> 6; v < n;
       v += wstride) {
    int o = off[v], c = cnt[v];
    ushort4 xv = *(const ushort4*)(x0h + (size_t)v * 64 + 4 * q);
    float t0 = tanhf(bf2f(xv.x)), t1 = tanhf(bf2f(xv.y)),
          t2 = tanhf(bf2f(xv.z)), t3 = tanhf(bf2f(xv.w));
    float dsum = 0.f;
    for (int t = g; t < c; t += 4) {
      int p = o + t;
      int r = prow[p];
      ushort4 ev = *(const ushort4*)(e1h + (size_t)r * 64 + 4 * q);
      float s = bf2f(ev.x) * t0 + bf2f(ev.y) * t1 + bf2f(ev.z) * t2 +
                bf2f(ev.w) * t3;
      // 4-lane reduce within intent (bits 0-1 of q)
      s += __shfl_xor(s, 1);
      s += __shfl_xor(s, 2);
      // softmax across intents (bits 2-3 of q)
      float m = fmaxf(s, __shfl_xor(s, 4));
      m = fmaxf(m, __shfl_xor(m, 8));
      float ee = expf(s - m);
      float se = ee + __shfl_xor(ee, 4);
      se += __shfl_xor(se, 8);
      float pr = ee / se;
      if ((q & 3) == 0) {
        s2csr[(size_t)p * 4 + k] = f2bf(pr);
        dsum += pr;
      }
    }
    dsum += __shfl_xor(dsum, 16);
    dsum += __shfl_xor(dsum, 32);
    if (g == 0 && (q & 3) == 0)
      dinv2[(size_t)v * 4 + k] = dsum > 0.f ? rsqrtf(dsum) : 0.f;
  }
}

// z0h[t] = bf16(dinv2[node,k(dim)] * x0[t])
static __global__ void k_zbuild(const float* __restrict__ dinv2,
                                const unsigned short* __restrict__ x0h,
                                long long total,
                                unsigned short* __restrict__ z0h) {
  long long stride = (long long)gridDim.x * blockDim.x;
  for (long long t = (long long)blockIdx.x * blockDim.x + threadIdx.x; t < total;
       t += stride) {
    float d2 = dinv2[((t >> 6) << 2) + ((t >> 4) & 3)];
    z0h[t] = f2bf(d2 * bf2f(x0h[t]));
  }
}

// wave/node: out[v*64+d] += dinv2[v,k]*sum_seg s2csr[p,k]*z0[r*64+d]
static __global__ void k_gather2(const int* __restrict__ off,
                                 const int* __restrict__ cnt,
                                 const int* __restrict__ prow, int n,
                                 const float* __restrict__ dinv2,
                                 const unsigned short* __restrict__ s2csr,
                                 const unsigned short* __restrict__ z0h,
                                 float* __restrict__ out) {
  int lane = threadIdx.x & 63;
  int q = lane & 15, g = lane >> 4, k = q >> 2;
  int wstride = (gridDim.x * blockDim.x) >> 6;
  for (int v = (blockIdx.x * blockDim.x + threadIdx.x) >> 6; v < n;
       v += wstride) {
    int o = off[v], c = cnt[v];
    float a0 = 0.f, a1 = 0.f, a2 = 0.f, a3 = 0.f;
    for (int t = g; t < c; t += 4) {
      int p = o + t;
      int r = prow[p];
      float w = bf2f(s2csr[(size_t)p * 4 + k]);
      ushort4 zv = *(const ushort4*)(z0h + (size_t)r * 64 + 4 * q);
      a0 += w * bf2f(zv.x);
      a1 += w * bf2f(zv.y);
      a2 += w * bf2f(zv.z);
      a3 += w * bf2f(zv.w);
    }
    a0 += __shfl_xor(a0, 16); a0 += __shfl_xor(a0, 32);
    a1 += __shfl_xor(a1, 16); a1 += __shfl_xor(a1, 32);
    a2 += __shfl_xor(a2, 16); a2 += __shfl_xor(a2, 32);
    a3 += __shfl_xor(a3, 16); a3 += __shfl_xor(a3, 32);
    if (g == 0) {
      float d2 = dinv2[(size_t)v * 4 + k];
      float4* po = (float4*)(out + (size_t)v * 64 + 4 * q);
      float4 cur = *po;
      cur.x += d2 * a0;
      cur.y += d2 * a1;
      cur.z += d2 * a2;
      cur.w += d2 * a3;
      *po = cur;
    }
  }
}

extern "C" void kernel_launch(void* const* d_in, const int* in_sizes, int n_in,
                              void* d_out, int out_size, void* d_ws,
                              size_t ws_size, hipStream_t stream) {
  const float* Gu = (const float*)d_in[0];
  const float* Gi = (const float*)d_in[1];
  const int* ei = (const int*)d_in[2];
  float* out = (float*)d_out;

  const int K = 64;
  int nu = in_sizes[0] / K;  // 100000
  int ni = in_sizes[1] / K;  // 50000
  int n = nu + ni;           // 150000
  int E = in_sizes[2] / 2;   // 2,000,000
  const int* row = ei;
  const int* col = ei + E;
  long long nK = (long long)n * K;

  // ws layout (all 16B-aligned for n=150000, E=2M):
  // dinv0f f32[n] | dinv2 f32[4n] | cnt[n] | off[n] | cursor[n] | ctr[4] |
  // prow[E] | s2csr u16[4E] | x0h u16[nK] | y0h u16[nK] | z0h u16[nK] |
  // e1h u16[nK]   (~106 MB)
  float* dinv0f = (float*)d_ws;
  float* dinv2 = dinv0f + n;
  int* cnt = (int*)(dinv2 + (size_t)n * 4);
  int* off = cnt + n;
  int* cursor = off + n;
  int* ctr = cursor + n;
  int* prow = ctr + 4;
  unsigned short* s2csr = (unsigned short*)(prow + E);
  unsigned short* x0h = s2csr + (size_t)E * 4;
  unsigned short* y0h = x0h + nK;
  unsigned short* z0h = y0h + nK;
  unsigned short* e1h = z0h + nK;

  // out = ego = concat(Gu, Gi)
  hipMemcpyAsync(out, Gu, (size_t)nu * K * sizeof(float),
                 hipMemcpyDeviceToDevice, stream);
  hipMemcpyAsync(out + (size_t)nu * K, Gi, (size_t)ni * K * sizeof(float),
                 hipMemcpyDeviceToDevice, stream);
  hipMemsetAsync(cnt, 0, (size_t)n * sizeof(int), stream);
  hipMemsetAsync(ctr, 0, 4 * sizeof(int), stream);

  const int B = 256;
  int gE = min((E + B - 1) / B, 4096);
  int gN = (n + B - 1) / B;  // 586
  int gW = (n + 3) / 4;      // wave-per-node, 4 waves/block

  // ---- CSR build ----
  k_cnt<<<gE, B, 0, stream>>>(col, E, cnt);
  k_alloc<<<gN, B, 0, stream>>>(cnt, n, off, cursor, dinv0f, ctr);
  k_fill<<<gE, B, 0, stream>>>(row, col, E, cursor, prow);

  // ---- bf16 tables ----
  k_cvt<<<2048, B, 0, stream>>>(out, dinv0f, nK, x0h, y0h);

  // ---- routing iter 1 (uniform intents) -> e1h ----
  k_gather1<<<gW, B, 0, stream>>>(off, cnt, prow, n, dinv0f, y0h, e1h);

  // ---- scores + softmax + deg2 fused -> s2csr, dinv2 ----
  k_score<<<gW, B, 0, stream>>>(off, cnt, prow, n, e1h, x0h, s2csr, dinv2);

  // ---- routing iter 2 ----
  k_zbuild<<<2048, B, 0, stream>>>(dinv2, x0h, nK, z0h);
  k_gather2<<<gW, B, 0, stream>>>(off, cnt, prow, n, dinv2, s2csr, z0h, out);
}

// Round 6
// 419.550 us; speedup vs baseline: 6.5982x; 1.4115x over previous
//
#include <hip/hip_runtime.h>

// DGCF round 6: scatter-free CSR build (linked list + prefix-sum + per-node
// compaction walk) and 8-deep gather groups (8 lanes x uint4 per row, 8 edges
// in flight per wave).
//   k_link:    next[e] = atomicExch(&head[col[e]], e)   (coalesced next write)
//   k_count:   cnt[v] = list length                      (walk, all waves resident)
//   k_bsum/k_bscan/k_off: node-ordered exclusive prefix -> off, dinv0
//   k_cvt:     x0h = bf16(ego), y0h = bf16(dinv0*ego)
//   k_compact: prow[off[v]+t] = row[e]  (wave-local contiguous writes)
//   gather1:   e1h[v] = bf16(0.25*dinv0[v]*sum_seg y0[r])
//   k_score:   s2csr[p] = softmax_k<e1h[r], tanh(x0[v])>; dinv2 fused
//   k_zbuild:  z0h = bf16(dinv2[.,k]*x0)
//   gather2:   out[v] += dinv2[v,k]*sum_seg s2csr[p,k]*z0[r]
// edge_index is int32.

__device__ __forceinline__ float bf2f(unsigned short h) {
  return __uint_as_float((unsigned)h << 16);
}
__device__ __forceinline__ unsigned short f2bf(float x) {
  unsigned u = __float_as_uint(x);
  return (unsigned short)((u + 0x7FFFu + ((u >> 16) & 1u)) >> 16);
}
__device__ __forceinline__ float lo16(unsigned u) {
  return __uint_as_float(u << 16);
}
__device__ __forceinline__ float hi16(unsigned u) {
  return __uint_as_float(u & 0xFFFF0000u);
}
__device__ __forceinline__ unsigned packbf(float lo, float hi) {
  return (unsigned)f2bf(lo) | ((unsigned)f2bf(hi) << 16);
}

#define RED8(M)                                        \
  a0 += __shfl_xor(a0, M); a1 += __shfl_xor(a1, M);    \
  a2 += __shfl_xor(a2, M); a3 += __shfl_xor(a3, M);    \
  a4 += __shfl_xor(a4, M); a5 += __shfl_xor(a5, M);    \
  a6 += __shfl_xor(a6, M); a7 += __shfl_xor(a7, M);

// next[e] = atomicExch(&head[col[e]], e); next write is coalesced.
static __global__ void k_link(const int* __restrict__ col, int E,
                              int* __restrict__ head, int* __restrict__ next) {
  int stride = gridDim.x * blockDim.x;
  for (int e = blockIdx.x * blockDim.x + threadIdx.x; e < E; e += stride)
    next[e] = atomicExch(&head[col[e]], e);
}

// cnt[v] = list length (serial walk; all waves co-resident hides latency)
static __global__ void k_count(const int* __restrict__ head,
                               const int* __restrict__ next, int n,
                               int* __restrict__ cnt) {
  int stride = gridDim.x * blockDim.x;
  for (int v = blockIdx.x * blockDim.x + threadIdx.x; v < n; v += stride) {
    int c = 0;
    for (int e = head[v]; e >= 0; e = next[e]) ++c;
    cnt[v] = c;
  }
}

// per-block sums of cnt
static __global__ void k_bsum(const int* __restrict__ cnt, int n,
                              int* __restrict__ bsum) {
  __shared__ int s[256];
  int v = blockIdx.x * 256 + threadIdx.x;
  s[threadIdx.x] = v < n ? cnt[v] : 0;
  __syncthreads();
  for (int d = 128; d > 0; d >>= 1) {
    if (threadIdx.x < d) s[threadIdx.x] += s[threadIdx.x + d];
    __syncthreads();
  }
  if (threadIdx.x == 0) bsum[blockIdx.x] = s[0];
}

// single-block exclusive scan of bsum (nb <= 1024)
static __global__ void k_bscan(int* __restrict__ bsum, int nb) {
  __shared__ int s[1024];
  int t = threadIdx.x;
  int orig = t < nb ? bsum[t] : 0;
  s[t] = orig;
  __syncthreads();
  for (int d = 1; d < 1024; d <<= 1) {
    int x = (t >= d) ? s[t - d] : 0;
    __syncthreads();
    s[t] += x;
    __syncthreads();
  }
  if (t < nb) bsum[t] = s[t] - orig;  // exclusive
}

// off[v] = bsum[block] + intra-block exclusive scan; dinv0 fused
static __global__ void k_off(const int* __restrict__ cnt,
                             const int* __restrict__ bsum, int n,
                             int* __restrict__ off,
                             float* __restrict__ dinv0f) {
  __shared__ int s[256];
  int t = threadIdx.x;
  int v = blockIdx.x * 256 + t;
  int c = v < n ? cnt[v] : 0;
  s[t] = c;
  __syncthreads();
  for (int d = 1; d < 256; d <<= 1) {
    int x = (t >= d) ? s[t - d] : 0;
    __syncthreads();
    s[t] += x;
    __syncthreads();
  }
  if (v < n) {
    off[v] = bsum[blockIdx.x] + s[t] - c;
    dinv0f[v] = c > 0 ? rsqrtf(0.25f * (float)c) : 0.f;
  }
}

// x0h = bf16(ego), y0h = bf16(dinv0[node]*ego)
static __global__ void k_cvt(const float* __restrict__ ego,
                             const float* __restrict__ dinv0f, long long total,
                             unsigned short* __restrict__ x0h,
                             unsigned short* __restrict__ y0h) {
  long long stride = (long long)gridDim.x * blockDim.x;
  for (long long t = (long long)blockIdx.x * blockDim.x + threadIdx.x; t < total;
       t += stride) {
    float v = ego[t];
    x0h[t] = f2bf(v);
    y0h[t] = f2bf(dinv0f[t >> 6] * v);
  }
}

// thread-per-node walk: prow[off[v]+t] = row[e]. With node-ordered off,
// a wave's 64 segments are contiguous -> wave-local full-line writes.
static __global__ void k_compact(const int* __restrict__ head,
                                 const int* __restrict__ next,
                                 const int* __restrict__ row,
                                 const int* __restrict__ off, int n,
                                 int* __restrict__ prow) {
  int stride = gridDim.x * blockDim.x;
  for (int v = blockIdx.x * blockDim.x + threadIdx.x; v < n; v += stride) {
    int p = off[v];
    for (int e = head[v]; e >= 0; e = next[e]) prow[p++] = row[e];
  }
}

// wave/node: lane q=lane&7 owns dims 8q..8q+7 (uint4), g=lane>>3 -> 8 edges in flight
// e1h[v] = bf16(0.25*dinv0[v] * sum_seg y0[r])
static __global__ void k_gather1(const int* __restrict__ off,
                                 const int* __restrict__ cnt,
                                 const int* __restrict__ prow, int n,
                                 const float* __restrict__ dinv0f,
                                 const unsigned short* __restrict__ y0h,
                                 unsigned short* __restrict__ e1h) {
  int lane = threadIdx.x & 63;
  int q = lane & 7, g = lane >> 3;
  int wstride = (gridDim.x * blockDim.x) >> 6;
  for (int v = (blockIdx.x * blockDim.x + threadIdx.x) >> 6; v < n;
       v += wstride) {
    int o = off[v], c = cnt[v];
    float a0 = 0.f, a1 = 0.f, a2 = 0.f, a3 = 0.f, a4 = 0.f, a5 = 0.f,
          a6 = 0.f, a7 = 0.f;
    for (int t = g; t < c; t += 8) {
      int r = prow[o + t];
      uint4 yv = *(const uint4*)(y0h + (size_t)r * 64 + 8 * q);
      a0 += lo16(yv.x); a1 += hi16(yv.x);
      a2 += lo16(yv.y); a3 += hi16(yv.y);
      a4 += lo16(yv.z); a5 += hi16(yv.z);
      a6 += lo16(yv.w); a7 += hi16(yv.w);
    }
    RED8(8) RED8(16) RED8(32)
    if (g == 0) {
      float sc = 0.25f * dinv0f[v];
      uint4 ov;
      ov.x = packbf(sc * a0, sc * a1);
      ov.y = packbf(sc * a2, sc * a3);
      ov.z = packbf(sc * a4, sc * a5);
      ov.w = packbf(sc * a6, sc * a7);
      *(uint4*)(e1h + (size_t)v * 64 + 8 * q) = ov;
    }
  }
}

// wave/node: score_k = <e1h[r], tanh(x0[v])>_k; s2csr[p]=softmax_k; dinv2 fused.
// intent k = q>>1 (each lane covers half an intent; shfl_xor(1) completes it).
static __global__ void k_score(const int* __restrict__ off,
                               const int* __restrict__ cnt,
                               const int* __restrict__ prow, int n,
                               const unsigned short* __restrict__ e1h,
                               const unsigned short* __restrict__ x0h,
                               unsigned short* __restrict__ s2csr,
                               float* __restrict__ dinv2) {
  int lane = threadIdx.x & 63;
  int q = lane & 7, g = lane >> 3, k = q >> 1;
  int wstride = (gridDim.x * blockDim.x) >> 6;
  for (int v = (blockIdx.x * blockDim.x + threadIdx.x) >> 6; v < n;
       v += wstride) {
    int o = off[v], c = cnt[v];
    uint4 xv = *(const uint4*)(x0h + (size_t)v * 64 + 8 * q);
    float t0 = tanhf(lo16(xv.x)), t1 = tanhf(hi16(xv.x)),
          t2 = tanhf(lo16(xv.y)), t3 = tanhf(hi16(xv.y)),
          t4 = tanhf(lo16(xv.z)), t5 = tanhf(hi16(xv.z)),
          t6 = tanhf(lo16(xv.w)), t7 = tanhf(hi16(xv.w));
    float dsum = 0.f;
    for (int t = g; t < c; t += 8) {
      int p = o + t;
      int r = prow[p];
      uint4 ev = *(const uint4*)(e1h + (size_t)r * 64 + 8 * q);
      float s = lo16(ev.x) * t0 + hi16(ev.x) * t1 + lo16(ev.y) * t2 +
                hi16(ev.y) * t3 + lo16(ev.z) * t4 + hi16(ev.z) * t5 +
                lo16(ev.w) * t6 + hi16(ev.w) * t7;
      s += __shfl_xor(s, 1);  // full 16-dim intent sum
      float m = fmaxf(s, __shfl_xor(s, 2));
      m = fmaxf(m, __shfl_xor(m, 4));
      float ee = expf(s - m);
      float se = ee + __shfl_xor(ee, 2);
      se += __shfl_xor(se, 4);
      float pr = ee / se;
      if (!(q & 1)) {
        s2csr[(size_t)p * 4 + k] = f2bf(pr);
        dsum += pr;
      }
    }
    dsum += __shfl_xor(dsum, 8);
    dsum += __shfl_xor(dsum, 16);
    dsum += __shfl_xor(dsum, 32);
    if (g == 0 && !(q & 1))
      dinv2[(size_t)v * 4 + k] = dsum > 0.f ? rsqrtf(dsum) : 0.f;
  }
}

// z0h[t] = bf16(dinv2[node,k(dim)] * x0[t])
static __global__ void k_zbuild(const float* __restrict__ dinv2,
                                const unsigned short* __restrict__ x0h,
                                long long total,
                                unsigned short* __restrict__ z0h) {
  long long stride = (long long)gridDim.x * blockDim.x;
  for (long long t = (long long)blockIdx.x * blockDim.x + threadIdx.x; t < total;
       t += stride) {
    float d2 = dinv2[((t >> 6) << 2) + ((t >> 4) & 3)];
    z0h[t] = f2bf(d2 * bf2f(x0h[t]));
  }
}

// wave/node: out[v] += dinv2[v,k] * sum_seg s2csr[p,k]*z0[r]
static __global__ void k_gather2(const int* __restrict__ off,
                                 const int* __restrict__ cnt,
                                 const int* __restrict__ prow, int n,
                                 const float* __restrict__ dinv2,
                                 const unsigned short* __restrict__ s2csr,
                                 const unsigned short* __restrict__ z0h,
                                 float* __restrict__ out) {
  int lane = threadIdx.x & 63;
  int q = lane & 7, g = lane >> 3, k = q >> 1;
  int wstride = (gridDim.x * blockDim.x) >> 6;
  for (int v = (blockIdx.x * blockDim.x + threadIdx.x) >> 6; v < n;
       v += wstride) {
    int o = off[v], c = cnt[v];
    float a0 = 0.f, a1 = 0.f, a2 = 0.f, a3 = 0.f, a4 = 0.f, a5 = 0.f,
          a6 = 0.f, a7 = 0.f;
    for (int t = g; t < c; t += 8) {
      int p = o + t;
      int r = prow[p];
      float w = bf2f(s2csr[(size_t)p * 4 + k]);
      uint4 zv = *(const uint4*)(z0h + (size_t)r * 64 + 8 * q);
      a0 += w * lo16(zv.x); a1 += w * hi16(zv.x);
      a2 += w * lo16(zv.y); a3 += w * hi16(zv.y);
      a4 += w * lo16(zv.z); a5 += w * hi16(zv.z);
      a6 += w * lo16(zv.w); a7 += w * hi16(zv.w);
    }
    RED8(8) RED8(16) RED8(32)
    if (g == 0) {
      float d2 = dinv2[(size_t)v * 4 + k];
      float* po = out + (size_t)v * 64 + 8 * q;
      float4 c0 = *(float4*)po;
      float4 c1 = *(float4*)(po + 4);
      c0.x += d2 * a0; c0.y += d2 * a1; c0.z += d2 * a2; c0.w += d2 * a3;
      c1.x += d2 * a4; c1.y += d2 * a5; c1.z += d2 * a6; c1.w += d2 * a7;
      *(float4*)po = c0;
      *(float4*)(po + 4) = c1;
    }
  }
}

extern "C" void kernel_launch(void* const* d_in, const int* in_sizes, int n_in,
                              void* d_out, int out_size, void* d_ws,
                              size_t ws_size, hipStream_t stream) {
  const float* Gu = (const float*)d_in[0];
  const float* Gi = (const float*)d_in[1];
  const int* ei = (const int*)d_in[2];
  float* out = (float*)d_out;

  const int K = 64;
  int nu = in_sizes[0] / K;  // 100000
  int ni = in_sizes[1] / K;  // 50000
  int n = nu + ni;           // 150000
  int E = in_sizes[2] / 2;   // 2,000,000
  const int* row = ei;
  const int* col = ei + E;
  long long nK = (long long)n * K;

  // ws layout: dinv0f f32[n] | dinv2 f32[4n] | cnt[n] | off[n] | head[n] |
  //   bsum[1024] | next[E] | prow[E] | s2csr u16[4E] | x0h|y0h|z0h|e1h u16[nK]
  //   (~114 MB)
  float* dinv0f = (float*)d_ws;
  float* dinv2 = dinv0f + n;
  int* cnt = (int*)(dinv2 + (size_t)n * 4);
  int* off = cnt + n;
  int* head = off + n;
  int* bsum = head + n;
  int* next = bsum + 1024;
  int* prow = next + E;
  unsigned short* s2csr = (unsigned short*)(prow + E);
  unsigned short* x0h = s2csr + (size_t)E * 4;
  unsigned short* y0h = x0h + nK;
  unsigned short* z0h = y0h + nK;
  unsigned short* e1h = z0h + nK;

  // out = ego = concat(Gu, Gi)
  hipMemcpyAsync(out, Gu, (size_t)nu * K * sizeof(float),
                 hipMemcpyDeviceToDevice, stream);
  hipMemcpyAsync(out + (size_t)nu * K, Gi, (size_t)ni * K * sizeof(float),
                 hipMemcpyDeviceToDevice, stream);
  hipMemsetAsync(head, 0xFF, (size_t)n * sizeof(int), stream);  // head = -1

  const int B = 256;
  int gE = min((E + B - 1) / B, 4096);
  int gN = (n + B - 1) / B;  // 586
  int nb = gN;               // prefix-scan blocks (<=1024)
  int gW = (n + 3) / 4;      // wave-per-node, 4 waves/block

  // ---- CSR build: link -> count -> scan -> compact ----
  k_link<<<gE, B, 0, stream>>>(col, E, head, next);
  k_count<<<gN, B, 0, stream>>>(head, next, n, cnt);
  k_bsum<<<nb, B, 0, stream>>>(cnt, n, bsum);
  k_bscan<<<1, 1024, 0, stream>>>(bsum, nb);
  k_off<<<nb, B, 0, stream>>>(cnt, bsum, n, off, dinv0f);
  k_compact<<<gN, B, 0, stream>>>(head, next, row, off, n, prow);

  // ---- bf16 tables ----
  k_cvt<<<2048, B, 0, stream>>>(out, dinv0f, nK, x0h, y0h);

  // ---- routing iter 1 (uniform intents) -> e1h ----
  k_gather1<<<gW, B, 0, stream>>>(off, cnt, prow, n, dinv0f, y0h, e1h);

  // ---- scores + softmax + deg2 fused -> s2csr, dinv2 ----
  k_score<<<gW, B, 0, stream>>>(off, cnt, prow, n, e1h, x0h, s2csr, dinv2);

  // ---- routing iter 2 ----
  k_zbuild<<<2048, B, 0, stream>>>(dinv2, x0h, nK, z0h);
  k_gather2<<<gW, B, 0, stream>>>(off, cnt, prow, n, dinv2, s2csr, z0h, out);
}

// Round 7
// 392.150 us; speedup vs baseline: 7.0592x; 1.0699x over previous
//
#include <hip/hip_runtime.h>

// DGCF round 7: counting-sort CSR build (hist -> scan -> partition -> bin),
// zero pointer-chasing, near-zero write amplification. Gathers: 8-deep
// (8 lanes x uint4 per row, 8 edges in flight per wave), as round 6.
//   k_hist:  ghist[b] = #edges with col>>8 == b        (LDS hist + block flush)
//   k_scan:  gbase = exclusive scan(ghist); gcur = copy
//   k_part:  pbuf[gcur[b]++] = (col,row)  (block-level range reservation)
//   k_bin:   per-bucket LDS bin -> cnt/off/dinv0f + prow (block-local region)
//   k_cvt:   x0h = bf16(ego), y0h = bf16(dinv0*ego)
//   gather1: e1h[v] = bf16(0.25*dinv0[v]*sum_seg y0[r])
//   k_score: s2csr[p] = softmax_k<e1h[r], tanh(x0[v])>; dinv2 fused
//   k_zbuild:z0h = bf16(dinv2[.,k]*x0)      (z0h region aliases pbuf)
//   gather2: out[v] += dinv2[v,k]*sum_seg s2csr[p,k]*z0[r]
// edge_index is int32.

__device__ __forceinline__ float bf2f(unsigned short h) {
  return __uint_as_float((unsigned)h << 16);
}
__device__ __forceinline__ unsigned short f2bf(float x) {
  unsigned u = __float_as_uint(x);
  return (unsigned short)((u + 0x7FFFu + ((u >> 16) & 1u)) >> 16);
}
__device__ __forceinline__ float lo16(unsigned u) {
  return __uint_as_float(u << 16);
}
__device__ __forceinline__ float hi16(unsigned u) {
  return __uint_as_float(u & 0xFFFF0000u);
}
__device__ __forceinline__ unsigned packbf(float lo, float hi) {
  return (unsigned)f2bf(lo) | ((unsigned)f2bf(hi) << 16);
}

#define RED8(M)                                        \
  a0 += __shfl_xor(a0, M); a1 += __shfl_xor(a1, M);    \
  a2 += __shfl_xor(a2, M); a3 += __shfl_xor(a3, M);    \
  a4 += __shfl_xor(a4, M); a5 += __shfl_xor(a5, M);    \
  a6 += __shfl_xor(a6, M); a7 += __shfl_xor(a7, M);

// ---- pass 1: bucket histogram (bucket = node >> 8) ----
static __global__ void k_hist(const int* __restrict__ col, int E, int NB,
                              int* __restrict__ ghist) {
  __shared__ int h[1024];
  for (int i = threadIdx.x; i < NB; i += 256) h[i] = 0;
  __syncthreads();
  int stride = gridDim.x * blockDim.x;
  for (int e = blockIdx.x * blockDim.x + threadIdx.x; e < E; e += stride)
    atomicAdd(&h[col[e] >> 8], 1);
  __syncthreads();
  for (int i = threadIdx.x; i < NB; i += 256)
    if (h[i]) atomicAdd(&ghist[i], h[i]);
}

// ---- exclusive scan of ghist (NB <= 1024), gcur = gbase ----
static __global__ void k_scan(const int* __restrict__ ghist, int NB,
                              int* __restrict__ gbase, int* __restrict__ gcur) {
  __shared__ int s[1024];
  int t = threadIdx.x;
  int c = t < NB ? ghist[t] : 0;
  s[t] = c;
  __syncthreads();
  for (int d = 1; d < 1024; d <<= 1) {
    int x = (t >= d) ? s[t - d] : 0;
    __syncthreads();
    s[t] += x;
    __syncthreads();
  }
  if (t < NB) {
    int ex = s[t] - c;
    gbase[t] = ex;
    gcur[t] = ex;
  }
}

// ---- pass 2: partition edges into bucket regions of pbuf ----
// One block per 8192-edge chunk; block-level range reservation per bucket.
static __global__ void k_part(const int* __restrict__ row,
                              const int* __restrict__ col, int E, int NB,
                              int* __restrict__ gcur, int2* __restrict__ pbuf) {
  __shared__ int lh[1024], lbase[1024], lcur[1024];
  int start = blockIdx.x * 8192;
  int end = min(start + 8192, E);
  for (int i = threadIdx.x; i < NB; i += 256) {
    lh[i] = 0;
    lcur[i] = 0;
  }
  __syncthreads();
  for (int e = start + threadIdx.x; e < end; e += 256)
    atomicAdd(&lh[col[e] >> 8], 1);
  __syncthreads();
  for (int i = threadIdx.x; i < NB; i += 256)
    if (lh[i]) lbase[i] = atomicAdd(&gcur[i], lh[i]);
  __syncthreads();
  for (int e = start + threadIdx.x; e < end; e += 256) {
    int v = col[e];
    int b = v >> 8;
    int lp = atomicAdd(&lcur[b], 1);
    pbuf[lbase[b] + lp] = make_int2(v, row[e]);
  }
}

// ---- pass 3: per-bucket bin -> cnt/off/dinv0f + prow ----
// Block b owns nodes [b*256, b*256+vcnt) and pbuf[gbase[b] .. +pcnt).
static __global__ void k_bin(const int2* __restrict__ pbuf,
                             const int* __restrict__ gbase,
                             const int* __restrict__ ghist, int n,
                             int* __restrict__ prow, int* __restrict__ cnt,
                             int* __restrict__ off,
                             float* __restrict__ dinv0f) {
  __shared__ int s[256];
  __shared__ int lcur[256];
  int t = threadIdx.x;
  int b = blockIdx.x;
  int vbase = b << 8;
  int vcnt = min(256, n - vbase);
  int pbase = gbase[b];
  int pcnt = ghist[b];
  lcur[t] = 0;
  __syncthreads();
  for (int p = t; p < pcnt; p += 256)
    atomicAdd(&lcur[pbuf[pbase + p].x - vbase], 1);
  __syncthreads();
  int c = (t < vcnt) ? lcur[t] : 0;
  s[t] = c;
  __syncthreads();
  for (int d = 1; d < 256; d <<= 1) {
    int x = (t >= d) ? s[t - d] : 0;
    __syncthreads();
    s[t] += x;
    __syncthreads();
  }
  int ex = s[t] - c;  // exclusive within bucket
  if (t < vcnt) {
    int v = vbase + t;
    cnt[v] = c;
    off[v] = pbase + ex;
    dinv0f[v] = c > 0 ? rsqrtf(0.25f * (float)c) : 0.f;
    lcur[t] = pbase + ex;  // global write cursor
  }
  __syncthreads();
  for (int p = t; p < pcnt; p += 256) {
    int2 pr = pbuf[pbase + p];
    int pos = atomicAdd(&lcur[pr.x - vbase], 1);
    prow[pos] = pr.y;
  }
}

// x0h = bf16(ego), y0h = bf16(dinv0[node]*ego)
static __global__ void k_cvt(const float* __restrict__ ego,
                             const float* __restrict__ dinv0f, long long total,
                             unsigned short* __restrict__ x0h,
                             unsigned short* __restrict__ y0h) {
  long long stride = (long long)gridDim.x * blockDim.x;
  for (long long t = (long long)blockIdx.x * blockDim.x + threadIdx.x; t < total;
       t += stride) {
    float v = ego[t];
    x0h[t] = f2bf(v);
    y0h[t] = f2bf(dinv0f[t >> 6] * v);
  }
}

// wave/node: lane q=lane&7 owns dims 8q..8q+7 (uint4), g=lane>>3 -> 8 edges in flight
static __global__ void k_gather1(const int* __restrict__ off,
                                 const int* __restrict__ cnt,
                                 const int* __restrict__ prow, int n,
                                 const float* __restrict__ dinv0f,
                                 const unsigned short* __restrict__ y0h,
                                 unsigned short* __restrict__ e1h) {
  int lane = threadIdx.x & 63;
  int q = lane & 7, g = lane >> 3;
  int wstride = (gridDim.x * blockDim.x) >> 6;
  for (int v = (blockIdx.x * blockDim.x + threadIdx.x) >> 6; v < n;
       v += wstride) {
    int o = off[v], c = cnt[v];
    float a0 = 0.f, a1 = 0.f, a2 = 0.f, a3 = 0.f, a4 = 0.f, a5 = 0.f,
          a6 = 0.f, a7 = 0.f;
    for (int t = g; t < c; t += 8) {
      int r = prow[o + t];
      uint4 yv = *(const uint4*)(y0h + (size_t)r * 64 + 8 * q);
      a0 += lo16(yv.x); a1 += hi16(yv.x);
      a2 += lo16(yv.y); a3 += hi16(yv.y);
      a4 += lo16(yv.z); a5 += hi16(yv.z);
      a6 += lo16(yv.w); a7 += hi16(yv.w);
    }
    RED8(8) RED8(16) RED8(32)
    if (g == 0) {
      float sc = 0.25f * dinv0f[v];
      uint4 ov;
      ov.x = packbf(sc * a0, sc * a1);
      ov.y = packbf(sc * a2, sc * a3);
      ov.z = packbf(sc * a4, sc * a5);
      ov.w = packbf(sc * a6, sc * a7);
      *(uint4*)(e1h + (size_t)v * 64 + 8 * q) = ov;
    }
  }
}

// wave/node: score_k = <e1h[r], tanh(x0[v])>_k; s2csr[p]=softmax_k; dinv2 fused.
static __global__ void k_score(const int* __restrict__ off,
                               const int* __restrict__ cnt,
                               const int* __restrict__ prow, int n,
                               const unsigned short* __restrict__ e1h,
                               const unsigned short* __restrict__ x0h,
                               unsigned short* __restrict__ s2csr,
                               float* __restrict__ dinv2) {
  int lane = threadIdx.x & 63;
  int q = lane & 7, g = lane >> 3, k = q >> 1;
  int wstride = (gridDim.x * blockDim.x) >> 6;
  for (int v = (blockIdx.x * blockDim.x + threadIdx.x) >> 6; v < n;
       v += wstride) {
    int o = off[v], c = cnt[v];
    uint4 xv = *(const uint4*)(x0h + (size_t)v * 64 + 8 * q);
    float t0 = tanhf(lo16(xv.x)), t1 = tanhf(hi16(xv.x)),
          t2 = tanhf(lo16(xv.y)), t3 = tanhf(hi16(xv.y)),
          t4 = tanhf(lo16(xv.z)), t5 = tanhf(hi16(xv.z)),
          t6 = tanhf(lo16(xv.w)), t7 = tanhf(hi16(xv.w));
    float dsum = 0.f;
    for (int t = g; t < c; t += 8) {
      int p = o + t;
      int r = prow[p];
      uint4 ev = *(const uint4*)(e1h + (size_t)r * 64 + 8 * q);
      float s = lo16(ev.x) * t0 + hi16(ev.x) * t1 + lo16(ev.y) * t2 +
                hi16(ev.y) * t3 + lo16(ev.z) * t4 + hi16(ev.z) * t5 +
                lo16(ev.w) * t6 + hi16(ev.w) * t7;
      s += __shfl_xor(s, 1);  // full 16-dim intent sum
      float m = fmaxf(s, __shfl_xor(s, 2));
      m = fmaxf(m, __shfl_xor(m, 4));
      float ee = expf(s - m);
      float se = ee + __shfl_xor(ee, 2);
      se += __shfl_xor(se, 4);
      float pr = ee / se;
      if (!(q & 1)) {
        s2csr[(size_t)p * 4 + k] = f2bf(pr);
        dsum += pr;
      }
    }
    dsum += __shfl_xor(dsum, 8);
    dsum += __shfl_xor(dsum, 16);
    dsum += __shfl_xor(dsum, 32);
    if (g == 0 && !(q & 1))
      dinv2[(size_t)v * 4 + k] = dsum > 0.f ? rsqrtf(dsum) : 0.f;
  }
}

// z0h[t] = bf16(dinv2[node,k(dim)] * x0[t])
static __global__ void k_zbuild(const float* __restrict__ dinv2,
                                const unsigned short* __restrict__ x0h,
                                long long total,
                                unsigned short* __restrict__ z0h) {
  long long stride = (long long)gridDim.x * blockDim.x;
  for (long long t = (long long)blockIdx.x * blockDim.x + threadIdx.x; t < total;
       t += stride) {
    float d2 = dinv2[((t >> 6) << 2) + ((t >> 4) & 3)];
    z0h[t] = f2bf(d2 * bf2f(x0h[t]));
  }
}

// wave/node: out[v] += dinv2[v,k] * sum_seg s2csr[p,k]*z0[r]
static __global__ void k_gather2(const int* __restrict__ off,
                                 const int* __restrict__ cnt,
                                 const int* __restrict__ prow, int n,
                                 const float* __restrict__ dinv2,
                                 const unsigned short* __restrict__ s2csr,
                                 const unsigned short* __restrict__ z0h,
                                 float* __restrict__ out) {
  int lane = threadIdx.x & 63;
  int q = lane & 7, g = lane >> 3, k = q >> 1;
  int wstride = (gridDim.x * blockDim.x) >> 6;
  for (int v = (blockIdx.x * blockDim.x + threadIdx.x) >> 6; v < n;
       v += wstride) {
    int o = off[v], c = cnt[v];
    float a0 = 0.f, a1 = 0.f, a2 = 0.f, a3 = 0.f, a4 = 0.f, a5 = 0.f,
          a6 = 0.f, a7 = 0.f;
    for (int t = g; t < c; t += 8) {
      int p = o + t;
      int r = prow[p];
      float w = bf2f(s2csr[(size_t)p * 4 + k]);
      uint4 zv = *(const uint4*)(z0h + (size_t)r * 64 + 8 * q);
      a0 += w * lo16(zv.x); a1 += w * hi16(zv.x);
      a2 += w * lo16(zv.y); a3 += w * hi16(zv.y);
      a4 += w * lo16(zv.z); a5 += w * hi16(zv.z);
      a6 += w * lo16(zv.w); a7 += w * hi16(zv.w);
    }
    RED8(8) RED8(16) RED8(32)
    if (g == 0) {
      float d2 = dinv2[(size_t)v * 4 + k];
      float* po = out + (size_t)v * 64 + 8 * q;
      float4 c0 = *(float4*)po;
      float4 c1 = *(float4*)(po + 4);
      c0.x += d2 * a0; c0.y += d2 * a1; c0.z += d2 * a2; c0.w += d2 * a3;
      c1.x += d2 * a4; c1.y += d2 * a5; c1.z += d2 * a6; c1.w += d2 * a7;
      *(float4*)po = c0;
      *(float4*)(po + 4) = c1;
    }
  }
}

extern "C" void kernel_launch(void* const* d_in, const int* in_sizes, int n_in,
                              void* d_out, int out_size, void* d_ws,
                              size_t ws_size, hipStream_t stream) {
  const float* Gu = (const float*)d_in[0];
  const float* Gi = (const float*)d_in[1];
  const int* ei = (const int*)d_in[2];
  float* out = (float*)d_out;

  const int K = 64;
  int nu = in_sizes[0] / K;  // 100000
  int ni = in_sizes[1] / K;  // 50000
  int n = nu + ni;           // 150000
  int E = in_sizes[2] / 2;   // 2,000,000
  const int* row = ei;
  const int* col = ei + E;
  long long nK = (long long)n * K;
  int NB = (n + 255) >> 8;  // 586 buckets (<= 1024)

  // ws layout: dinv0f f32[n] | dinv2 f32[4n] | cnt[n] | off[n] |
  //   ghist[1024] | gbase[1024] | gcur[1024] | prow[E] | s2csr u16[4E] |
  //   x0h u16[nK] | y0h u16[nK] | z0h u16[nK] (pbuf int2[E] aliases z0h) |
  //   e1h u16[nK]    (~105 MB)
  float* dinv0f = (float*)d_ws;
  float* dinv2 = dinv0f + n;
  int* cnt = (int*)(dinv2 + (size_t)n * 4);
  int* off = cnt + n;
  int* ghist = off + n;
  int* gbase = ghist + 1024;
  int* gcur = gbase + 1024;
  int* prow = gcur + 1024;
  unsigned short* s2csr = (unsigned short*)(prow + E);
  unsigned short* x0h = s2csr + (size_t)E * 4;
  unsigned short* y0h = x0h + nK;
  unsigned short* z0h = y0h + nK;
  int2* pbuf = (int2*)z0h;  // dead before k_zbuild runs
  unsigned short* e1h = z0h + nK;

  // out = ego = concat(Gu, Gi)
  hipMemcpyAsync(out, Gu, (size_t)nu * K * sizeof(float),
                 hipMemcpyDeviceToDevice, stream);
  hipMemcpyAsync(out + (size_t)nu * K, Gi, (size_t)ni * K * sizeof(float),
                 hipMemcpyDeviceToDevice, stream);
  hipMemsetAsync(ghist, 0, 1024 * sizeof(int), stream);

  const int B = 256;
  int gE = min((E + B - 1) / B, 4096);
  int gW = (n + 3) / 4;  // wave-per-node, 4 waves/block

  // ---- CSR build: hist -> scan -> partition -> bin ----
  k_hist<<<gE, B, 0, stream>>>(col, E, NB, ghist);
  k_scan<<<1, 1024, 0, stream>>>(ghist, NB, gbase, gcur);
  k_part<<<(E + 8191) / 8192, B, 0, stream>>>(row, col, E, NB, gcur, pbuf);
  k_bin<<<NB, B, 0, stream>>>(pbuf, gbase, ghist, n, prow, cnt, off, dinv0f);

  // ---- bf16 tables ----
  k_cvt<<<2048, B, 0, stream>>>(out, dinv0f, nK, x0h, y0h);

  // ---- routing iter 1 (uniform intents) -> e1h ----
  k_gather1<<<gW, B, 0, stream>>>(off, cnt, prow, n, dinv0f, y0h, e1h);

  // ---- scores + softmax + deg2 fused -> s2csr, dinv2 ----
  k_score<<<gW, B, 0, stream>>>(off, cnt, prow, n, e1h, x0h, s2csr, dinv2);

  // ---- routing iter 2 ----
  k_zbuild<<<2048, B, 0, stream>>>(dinv2, x0h, nK, z0h);
  k_gather2<<<gW, B, 0, stream>>>(off, cnt, prow, n, dinv2, s2csr, z0h, out);
}